// Round 9
// baseline (633.172 us; speedup 1.0000x reference)
//
#include <hip/hip_runtime.h>
#include <hip/hip_bf16.h>
#include <cstdint>

#define NEG_SLOPE 0.2f

typedef __bf16 bf16x8 __attribute__((ext_vector_type(8)));
typedef _Float16 half8 __attribute__((ext_vector_type(8)));
typedef float  floatx4 __attribute__((ext_vector_type(4)));

// ---------- bf16 helpers ----------
__device__ __forceinline__ float us2f(unsigned short u) {
    union { unsigned int i; float f; } c; c.i = ((unsigned int)u) << 16; return c.f;
}
__device__ __forceinline__ unsigned short f2us(float f) {
    union { float f; unsigned int i; } c; c.f = f;
    unsigned int x = c.i;
    unsigned int r = (x + 0x7fffu + ((x >> 16) & 1u)) >> 16;   // RNE
    return (unsigned short)r;
}
__device__ __forceinline__ unsigned short f2h(float f) {
    union { _Float16 h; unsigned short u; } c; c.h = (_Float16)f; return c.u;
}
__device__ __forceinline__ float h2f(unsigned short u) {
    union { _Float16 h; unsigned short u; } c; c.u = u; return (float)c.h;
}
__device__ __forceinline__ float ldx(const void* p, int i, int bf) {
    return bf ? us2f(((const unsigned short*)p)[i]) : ((const float*)p)[i];
}
__device__ __forceinline__ void split2(float f, unsigned short& h, unsigned short& l) {
    h = f2us(f);
    l = f2us(f - us2f(h));
}
__device__ __forceinline__ float sel4(const float* a, int i) {
    float lo = (i & 1) ? a[1] : a[0];
    float hi = (i & 1) ? a[3] : a[2];
    return (i & 2) ? hi : lo;
}
__device__ __forceinline__ void unp8(uint4 u, float* f) {
    union { unsigned int i; float ff; } a;
    a.i = u.x << 16;          f[0] = a.ff;
    a.i = u.x & 0xffff0000u;  f[1] = a.ff;
    a.i = u.y << 16;          f[2] = a.ff;
    a.i = u.y & 0xffff0000u;  f[3] = a.ff;
    a.i = u.z << 16;          f[4] = a.ff;
    a.i = u.z & 0xffff0000u;  f[5] = a.ff;
    a.i = u.w << 16;          f[6] = a.ff;
    a.i = u.w & 0xffff0000u;  f[7] = a.ff;
}

// ---------- runtime dtype probes ----------
__global__ void k_detect(const unsigned short* __restrict__ x16,
                         const unsigned int* __restrict__ ei,
                         int* __restrict__ flags) {
    if (threadIdx.x == 0 && blockIdx.x == 0) {
        int cnt = 0;
        for (int i = 0; i < 1024; ++i) {
            const unsigned short u = x16[2 * i];
            const int e = (u >> 7) & 0xFF;
            if (e < 100 || e > 160) ++cnt;
        }
        flags[0] = (cnt < 256) ? 1 : 0;      // bf16?
        int is64 = 1;
        for (int i = 0; i < 64; ++i)
            if (ei[2 * i + 1] != 0u) { is64 = 0; break; }
        flags[1] = is64;                      // int64?
    }
}

__device__ __forceinline__ int edge_at(const void* ei, int f64, long long idx) {
    if (f64) return (int)((const long long*)ei)[idx];
    return ((const int*)ei)[idx];
}

// ---------- CSR build ----------
__global__ void k_hist(const void* __restrict__ ei, const int* __restrict__ flags,
                       int* __restrict__ deg, int E, int N) {
    const int f64 = flags[1];
    const int EP = E + N;
    for (int e = blockIdx.x * blockDim.x + threadIdx.x; e < EP; e += gridDim.x * blockDim.x) {
        int dst = (e < E) ? edge_at(ei, f64, (long long)E + e) : (e - E);
        atomicAdd(&deg[dst], 1);
    }
}

__global__ __launch_bounds__(1024) void k_scan_a(const int* __restrict__ deg,
                                                 int* __restrict__ coff,
                                                 int* __restrict__ part, int N) {
    __shared__ int tmp[1024];
    const int t = threadIdx.x, idx = blockIdx.x * 1024 + t;
    const int v = (idx < N) ? deg[idx] : 0;
    tmp[t] = v; __syncthreads();
    for (int s = 1; s < 1024; s <<= 1) {
        int a = (t >= s) ? tmp[t - s] : 0;
        __syncthreads(); tmp[t] += a; __syncthreads();
    }
    if (idx < N) coff[idx] = tmp[t] - v;
    if (t == 1023) part[blockIdx.x] = tmp[1023];
}

__global__ __launch_bounds__(1024) void k_scan_b(int* __restrict__ part,
                                                 int* __restrict__ coff, int nblk, int N) {
    __shared__ int tmp[1024];
    const int t = threadIdx.x;
    const int v = (t < nblk) ? part[t] : 0;
    tmp[t] = v; __syncthreads();
    for (int s = 1; s < 1024; s <<= 1) {
        int a = (t >= s) ? tmp[t - s] : 0;
        __syncthreads(); tmp[t] += a; __syncthreads();
    }
    if (t < nblk) part[t] = tmp[t] - v;
    if (t == 1023) coff[N] = tmp[1023];
}

__global__ __launch_bounds__(1024) void k_scan_c(int* __restrict__ coff,
                                                 const int* __restrict__ part, int N) {
    const int idx = blockIdx.x * 1024 + threadIdx.x;
    if (idx < N) coff[idx] += part[blockIdx.x];
}

__global__ void k_scatter(const void* __restrict__ ei, const int* __restrict__ flags,
                          const int* __restrict__ coff, int* __restrict__ cpos,
                          int* __restrict__ csrc, int E, int N) {
    const int f64 = flags[1];
    const int EP = E + N;
    for (int e = blockIdx.x * blockDim.x + threadIdx.x; e < EP; e += gridDim.x * blockDim.x) {
        int src, dst;
        if (e < E) { src = edge_at(ei, f64, e); dst = edge_at(ei, f64, (long long)E + e); }
        else       { src = dst = e - E; }
        const int p = atomicAdd(&cpos[dst], 1);
        csrc[coff[dst] + p] = src;
    }
}

// ---------- W -> MFMA B-fragment pre-shuffle (hi/lo planes) ----------
// F16=0: bf16 hi/lo planes (layers 1-2). F16=1: f16 hi/lo planes (layer 3).
template <int F16>
__global__ void k_wfrag(const void* __restrict__ Wv, const int* __restrict__ flags,
                        int wstride, int total,
                        unsigned short* __restrict__ outH, unsigned short* __restrict__ outL) {
    const int bf = flags[0];
    for (int tid = blockIdx.x * blockDim.x + threadIdx.x; tid < total;
         tid += gridDim.x * blockDim.x) {
        const int j    = tid & 7;
        const int lane = (tid >> 3) & 63;
        const int ks   = (tid >> 9) & 3;
        const int ntg  = (tid >> 11) & 7;
        const int blk  = tid >> 14;
        const int k = ks * 32 + (lane >> 4) * 8 + j;
        const int c = blk * 128 + ntg * 16 + (lane & 15);
        const float v = ldx(Wv, k * wstride + c, bf);
        unsigned short h, l;
        if (F16) {
            h = f2h(v);
            l = f2h(v - h2f(h));
        } else {
            split2(v, h, l);
        }
        outH[tid] = h; outL[tid] = l;
    }
}

// ---------- layers 1-2: va[k,h] = sum_c W[k,h*32+c]*a[h,c] -> B-fragment ----------
// Fragment layout [head][ks][lane][8]: col (lane&15) 0 = va_src, 1 = va_dst, else 0.
// Feeds the in-GEMM score MFMA (replaces the shfl-reduce epilogue).
__global__ void k_vaf(const void* __restrict__ W, const void* __restrict__ as,
                      const void* __restrict__ ad, const int* __restrict__ flags,
                      unsigned short* __restrict__ outH, unsigned short* __restrict__ outL) {
    const int bf = flags[0];
    const int tid = blockIdx.x * blockDim.x + threadIdx.x;
    if (tid >= 8192) return;
    const int j    = tid & 7;
    const int lane = (tid >> 3) & 63;
    const int ks   = (tid >> 9) & 3;
    const int head = (tid >> 11) & 3;
    const int k    = ks * 32 + (lane >> 4) * 8 + j;
    const int col  = lane & 15;
    float v = 0.f;
    if (col < 2) {
        const void* a = col ? ad : as;
        float acc = 0.f;
        for (int c = 0; c < 32; ++c)
            acc = fmaf(ldx(W, k * 128 + head * 32 + c, bf), ldx(a, head * 32 + c, bf), acc);
        v = acc;
    }
    unsigned short h, l; split2(v, h, l);
    outH[tid] = h; outL[tid] = l;
}

// ---------- va[k,h] = sum_c W3[k, h*128+c] * a[h,c]  (layer-3 score folding) ----------
__global__ void k_wa(const void* __restrict__ W, const void* __restrict__ as,
                     const void* __restrict__ ad, const int* __restrict__ flags,
                     float* __restrict__ va) {
    const int bf = flags[0];
    const int t = blockIdx.x * blockDim.x + threadIdx.x;
    if (t >= 512) return;
    const int k = t >> 2, h = t & 3;
    float ss = 0.f, dd = 0.f;
    for (int c = 0; c < 128; ++c) {
        const float w = ldx(W, k * 512 + h * 128 + c, bf);
        ss = fmaf(w, ldx(as, h * 128 + c, bf), ss);
        dd = fmaf(w, ldx(ad, h * 128 + c, bf), dd);
    }
    va[k * 8 + h] = ss;
    va[k * 8 + 4 + h] = dd;
}

// ---------- MFMA GEMM, scores via extra MFMA columns (no shfl epilogue) ----------
// AM=0: layer 1 (X raw bf16 if bf, else f32 split). AM=1: layer 2 (X = hi/lo planes).
template <int AM>
__global__ __launch_bounds__(256) void k_gemm(const void* __restrict__ Xv,
                                              const void* __restrict__ Xlv,
                                              const unsigned short* __restrict__ whf,
                                              const unsigned short* __restrict__ wlf,
                                              const unsigned short* __restrict__ vfh,
                                              const unsigned short* __restrict__ vfl,
                                              unsigned short* __restrict__ Y16,
                                              float* __restrict__ ssrc,
                                              float* __restrict__ sdst,
                                              const int* __restrict__ flags,
                                              int N) {
    __shared__ __align__(16) unsigned short Ah[64][136], Al[64][136];
    const int bf   = flags[0];
    const int t    = threadIdx.x;
    const int row0 = blockIdx.x * 64;
    const int wv   = t >> 6;
    const int lane = t & 63;
    const int quad = lane >> 4;
    const int l16  = lane & 15;

#pragma unroll
    for (int it = 0; it < 8; ++it) {
        const int id = it * 256 + t;
        const int r  = id >> 5;
        const int c  = (id & 31) * 4;
        const int gr = row0 + r;
        ushort4 h4 = make_ushort4(0, 0, 0, 0), l4 = make_ushort4(0, 0, 0, 0);
        if (gr < N) {
            if (AM == 1) {
                h4 = *(const ushort4*)&((const unsigned short*)Xv)[(size_t)gr * 128 + c];
                l4 = *(const ushort4*)&((const unsigned short*)Xlv)[(size_t)gr * 128 + c];
            } else if (bf) {
                h4 = *(const ushort4*)&((const unsigned short*)Xv)[(size_t)gr * 128 + c];
            } else {
                const float4 f = *(const float4*)&((const float*)Xv)[(size_t)gr * 128 + c];
                split2(f.x, h4.x, l4.x); split2(f.y, h4.y, l4.y);
                split2(f.z, h4.z, l4.z); split2(f.w, h4.w, l4.w);
            }
        }
        *(ushort4*)&Ah[r][c] = h4;
        *(ushort4*)&Al[r][c] = l4;
    }
    __syncthreads();

    floatx4 acc[4][2];
    floatx4 accS[4];
#pragma unroll
    for (int mt = 0; mt < 4; ++mt) {
        accS[mt] = (floatx4){0.f, 0.f, 0.f, 0.f};
#pragma unroll
        for (int nt = 0; nt < 2; ++nt) acc[mt][nt] = (floatx4){0.f, 0.f, 0.f, 0.f};
    }

#pragma unroll
    for (int ks = 0; ks < 4; ++ks) {
        const int ko = ks * 32 + quad * 8;
        const bool useAl = (AM == 1) || !bf;
        bf16x8 ah[4], al[4], bh[2], bl[2], vh, vl;
#pragma unroll
        for (int mt = 0; mt < 4; ++mt) ah[mt] = *(const bf16x8*)&Ah[mt * 16 + l16][ko];
        if (useAl) {
#pragma unroll
            for (int mt = 0; mt < 4; ++mt) al[mt] = *(const bf16x8*)&Al[mt * 16 + l16][ko];
        }
#pragma unroll
        for (int nt = 0; nt < 2; ++nt)
            bh[nt] = *(const bf16x8*)&whf[(((wv * 2 + nt) * 4 + ks) * 64 + lane) * 8];
        if (!bf) {
#pragma unroll
            for (int nt = 0; nt < 2; ++nt)
                bl[nt] = *(const bf16x8*)&wlf[(((wv * 2 + nt) * 4 + ks) * 64 + lane) * 8];
        }
        vh = *(const bf16x8*)&vfh[((wv * 4 + ks) * 64 + lane) * 8];
        vl = *(const bf16x8*)&vfl[((wv * 4 + ks) * 64 + lane) * 8];

#pragma unroll
        for (int mt = 0; mt < 4; ++mt) {
#pragma unroll
            for (int nt = 0; nt < 2; ++nt) {
                acc[mt][nt] = __builtin_amdgcn_mfma_f32_16x16x32_bf16(ah[mt], bh[nt], acc[mt][nt], 0, 0, 0);
                if (!bf)
                    acc[mt][nt] = __builtin_amdgcn_mfma_f32_16x16x32_bf16(ah[mt], bl[nt], acc[mt][nt], 0, 0, 0);
                if ((AM == 1) || !bf)
                    acc[mt][nt] = __builtin_amdgcn_mfma_f32_16x16x32_bf16(al[mt], bh[nt], acc[mt][nt], 0, 0, 0);
            }
            // score columns: col0 = s_src, col1 = s_dst (f32-exact via hi+lo va)
            accS[mt] = __builtin_amdgcn_mfma_f32_16x16x32_bf16(ah[mt], vh, accS[mt], 0, 0, 0);
            accS[mt] = __builtin_amdgcn_mfma_f32_16x16x32_bf16(ah[mt], vl, accS[mt], 0, 0, 0);
            if ((AM == 1) || !bf)
                accS[mt] = __builtin_amdgcn_mfma_f32_16x16x32_bf16(al[mt], vh, accS[mt], 0, 0, 0);
        }
    }

#pragma unroll
    for (int mt = 0; mt < 4; ++mt) {
        const int rl = mt * 16 + quad * 4;
#pragma unroll
        for (int r = 0; r < 4; ++r) {
            const int grow = row0 + rl + r;
            if (grow < N) {
#pragma unroll
                for (int nt = 0; nt < 2; ++nt)
                    Y16[(size_t)grow * 128 + wv * 32 + nt * 16 + l16] =
                        f2us(acc[mt][nt][r]);
                if (l16 == 0)      ssrc[(size_t)grow * 4 + wv] = accS[mt][r];
                else if (l16 == 1) sdst[(size_t)grow * 4 + wv] = accS[mt][r];
            }
        }
    }
}

// ---------- softmax + aggregation; 16 lanes/node; shfl-broadcast fast path ----------
// NO-MAX softmax (layers 1-2 scores ~N(0,11), max << 88 overflow; guarded fmin 80).
// Both modes write hi/lo bf16 planes (outH/outL).
// MODE 0: x1 = elu(acc + bias + raw resid)            (resid = input x, bf/f32)
// MODE 1: x2 = elu(acc + bias + (residH+residL));     also layer-3 scores via va
template <int MODE>
__global__ __launch_bounds__(256) void k_agg(const int* __restrict__ coff,
                                             const int* __restrict__ csrc,
                                             const float* __restrict__ ssrc,
                                             const float* __restrict__ sdst,
                                             const unsigned short* __restrict__ H16,
                                             const void* __restrict__ bias,
                                             const void* __restrict__ resid,
                                             const unsigned short* __restrict__ residL,
                                             const int* __restrict__ flags,
                                             int N,
                                             const float* __restrict__ va,
                                             float* __restrict__ ss2,
                                             float* __restrict__ sd2,
                                             unsigned short* __restrict__ outH,
                                             unsigned short* __restrict__ outL) {
    __shared__ float vaS[(MODE == 1) ? 128 : 1][10];   // pad 9->10: 4-way -> 2-way banks
    const int bf   = flags[0];
    const int t    = threadIdx.x;
    const int l16  = t & 15;
    const int n0   = blockIdx.x * 16 + (t >> 4);
    const bool nact = n0 < N;
    const int n    = nact ? n0 : (N - 1);
    const int beg = coff[n], end = coff[n + 1];
    const int deg = end - beg;

    if (MODE == 1) {
        for (int i = t; i < 1024; i += 256) vaS[i >> 3][i & 7] = va[i];
        __syncthreads();
    }

    const float4 sdv = *(const float4*)&sdst[(size_t)n * 4];
    const float sd[4] = { sdv.x, sdv.y, sdv.z, sdv.w };
    const bool fast = (deg <= 16);
    float z[4];
    int   myS = 0;
    float wn[4] = { 0.f, 0.f, 0.f, 0.f };     // raw exp weights (unnormalized)

    if (fast) {
        const bool act = l16 < deg;
        if (act) {
            myS = csrc[beg + l16];
            const float4 sp = *(const float4*)&ssrc[(size_t)myS * 4];
            const float s4[4] = { sp.x, sp.y, sp.z, sp.w };
#pragma unroll
            for (int h = 0; h < 4; ++h) {
                float tv = s4[h] + sd[h];
                tv = tv >= 0.f ? tv : NEG_SLOPE * tv;
                wn[h] = __expf(fminf(tv, 80.f));
            }
        }
#pragma unroll
        for (int h = 0; h < 4; ++h) z[h] = wn[h];
#pragma unroll
        for (int mk = 1; mk <= 8; mk <<= 1)
#pragma unroll
            for (int h = 0; h < 4; ++h) z[h] += __shfl_xor(z[h], mk);
    } else {
#pragma unroll
        for (int h = 0; h < 4; ++h) z[h] = 0.f;
        for (int e = beg + l16; e < end; e += 16) {
            const int s = csrc[e];
            const float4 sp = *(const float4*)&ssrc[(size_t)s * 4];
            const float s4[4] = { sp.x, sp.y, sp.z, sp.w };
#pragma unroll
            for (int h = 0; h < 4; ++h) {
                float tv = s4[h] + sd[h];
                tv = tv >= 0.f ? tv : NEG_SLOPE * tv;
                z[h] += __expf(fminf(tv, 80.f));
            }
        }
#pragma unroll
        for (int mk = 1; mk <= 8; mk <<= 1)
#pragma unroll
            for (int h = 0; h < 4; ++h) z[h] += __shfl_xor(z[h], mk);
    }

    float ivz[4];
#pragma unroll
    for (int h = 0; h < 4; ++h) ivz[h] = 1.f / (z[h] + 1e-16f);

    // gather: each lane owns 8 channels of its node (uint4 = 16 B per lane per edge)
    const int c8 = l16 * 8;
    const int hd = l16 >> 2;             // head owning channels c8..c8+7
    const float ih = sel4(ivz, hd);      // end-scale (1/z for this lane's head)
    float ac[8];
#pragma unroll
    for (int j = 0; j < 8; ++j) ac[j] = 0.f;

    if (fast) {
        for (int e = 0; e < deg; ++e) {
            const int s = __shfl(myS, e, 16);
            float wa4[4];
            wa4[0] = __shfl(wn[0], e, 16);
            wa4[1] = __shfl(wn[1], e, 16);
            wa4[2] = __shfl(wn[2], e, 16);
            wa4[3] = __shfl(wn[3], e, 16);
            const float w = sel4(wa4, hd);
            const uint4 u = *(const uint4*)&H16[(size_t)s * 128 + c8];
            float f[8]; unp8(u, f);
#pragma unroll
            for (int j = 0; j < 8; ++j) ac[j] = fmaf(w, f[j], ac[j]);
        }
    } else {
        const float sdh = sel4(sd, hd);
        for (int e = beg; e < end; ++e) {
            const int s = csrc[e];
            float tv = ssrc[(size_t)s * 4 + hd] + sdh;
            tv = tv >= 0.f ? tv : NEG_SLOPE * tv;
            const float w = __expf(fminf(tv, 80.f));
            const uint4 u = *(const uint4*)&H16[(size_t)s * 128 + c8];
            float f[8]; unp8(u, f);
#pragma unroll
            for (int j = 0; j < 8; ++j) ac[j] = fmaf(w, f[j], ac[j]);
        }
    }

    // normalize once (softmax 1/z)
#pragma unroll
    for (int j = 0; j < 8; ++j) ac[j] *= ih;

    if (!nact) return;
    const int ob = n * 128 + c8;
    float rr[8];
    if (MODE == 0) {
        if (bf) {
            const uint4 u = *(const uint4*)&((const unsigned short*)resid)[ob];
            unp8(u, rr);
        } else {
            const float4 r0 = *(const float4*)&((const float*)resid)[ob];
            const float4 r1 = *(const float4*)&((const float*)resid)[ob + 4];
            rr[0] = r0.x; rr[1] = r0.y; rr[2] = r0.z; rr[3] = r0.w;
            rr[4] = r1.x; rr[5] = r1.y; rr[6] = r1.z; rr[7] = r1.w;
        }
    } else {
        const uint4 uh = *(const uint4*)&((const unsigned short*)resid)[ob];
        const uint4 ul = *(const uint4*)&residL[ob];
        float fh[8], fl[8]; unp8(uh, fh); unp8(ul, fl);
#pragma unroll
        for (int j = 0; j < 8; ++j) rr[j] = fh[j] + fl[j];
    }
    float o[8];
#pragma unroll
    for (int j = 0; j < 8; ++j) {
        const float v = ac[j] + ldx(bias, c8 + j, bf) + rr[j];
        o[j] = v > 0.f ? v : expm1f(v);
    }

    // hi/lo bf16 planes (hi feeds next layer's raw-A / gather; hi+lo = ~f32 resid)
    unsigned short hi[8], lo[8];
#pragma unroll
    for (int j = 0; j < 8; ++j) {
        hi[j] = f2us(o[j]);
        lo[j] = f2us(o[j] - us2f(hi[j]));
    }
    uint4 uh, ul;
    uh.x = (unsigned int)hi[0] | ((unsigned int)hi[1] << 16);
    uh.y = (unsigned int)hi[2] | ((unsigned int)hi[3] << 16);
    uh.z = (unsigned int)hi[4] | ((unsigned int)hi[5] << 16);
    uh.w = (unsigned int)hi[6] | ((unsigned int)hi[7] << 16);
    ul.x = (unsigned int)lo[0] | ((unsigned int)lo[1] << 16);
    ul.y = (unsigned int)lo[2] | ((unsigned int)lo[3] << 16);
    ul.z = (unsigned int)lo[4] | ((unsigned int)lo[5] << 16);
    ul.w = (unsigned int)lo[6] | ((unsigned int)lo[7] << 16);
    *(uint4*)&outH[ob] = uh;
    *(uint4*)&outL[ob] = ul;

    if (MODE == 1) {
        // layer-3 scores: s[n,h] = sum_k x2[n,k] * va[k,h] (f32-exact)
        float p[8];
#pragma unroll
        for (int o8 = 0; o8 < 8; ++o8) {
            float acc = 0.f;
#pragma unroll
            for (int j = 0; j < 8; ++j) acc = fmaf(o[j], vaS[c8 + j][o8], acc);
            p[o8] = acc;
        }
#pragma unroll
        for (int mk = 1; mk <= 8; mk <<= 1)
#pragma unroll
            for (int o8 = 0; o8 < 8; ++o8) p[o8] += __shfl_xor(p[o8], mk);
        if (l16 == 0) {
#pragma unroll
            for (int h = 0; h < 4; ++h) {
                ss2[(size_t)n * 4 + h] = p[h];
                sd2[(size_t)n * 4 + h] = p[4 + h];
            }
        }
    }
}

// ---------- FUSED layer 3: aggregate-first gather -> LDS -> K=512 MFMA GEMM ----------
// 16 nodes/block (LDS 17.4KB -> 8 blocks/CU). Phase 1: 16 lanes/node gather x2h
// (bf16, 25.6MB table) with max-subtracted softmax, aggregate per head into
// f16 LDS tile aggS[4 kc][16 rows][136]. Phase 2: GEMM vs whf3 hi-plane only,
// epilogue adds bias + hi/lo-bf16 residual, writes d_out.
__global__ __launch_bounds__(256) void k_aggx3(const int* __restrict__ coff,
                                               const int* __restrict__ csrc,
                                               const float* __restrict__ ssrc,
                                               const float* __restrict__ sdst,
                                               const unsigned short* __restrict__ X16,
                                               const unsigned short* __restrict__ Xl16,
                                               const unsigned short* __restrict__ whf,
                                               const void* __restrict__ bias,
                                               const int* __restrict__ flags,
                                               void* __restrict__ out, int N) {
    __shared__ __align__(16) unsigned short aggS[4][16][136];
    const int bf   = flags[0];
    const int t    = threadIdx.x;
    const int row0 = blockIdx.x * 16;
    const int l16  = t & 15;

    // ---- phase 1: aggregate 16 nodes into LDS (16 lanes per node)
    {
        const int r  = t >> 4;
        const int n0 = row0 + r;
        const int n  = (n0 < N) ? n0 : (N - 1);
        const int beg = coff[n], end = coff[n + 1];
        const int deg = end - beg;

        const float4 sdv = *(const float4*)&sdst[(size_t)n * 4];
        const float sd[4] = { sdv.x, sdv.y, sdv.z, sdv.w };
        const bool fast = (deg <= 16);
        float m[4], z[4];
        int   myS = 0;
        float wn[4] = { 0.f, 0.f, 0.f, 0.f };

        if (fast) {
            const bool act = l16 < deg;
            float v[4];
#pragma unroll
            for (int h = 0; h < 4; ++h) v[h] = -1e30f;
            if (act) {
                myS = csrc[beg + l16];
                const float4 sp = *(const float4*)&ssrc[(size_t)myS * 4];
                const float s4[4] = { sp.x, sp.y, sp.z, sp.w };
#pragma unroll
                for (int h = 0; h < 4; ++h) {
                    float tv = s4[h] + sd[h];
                    v[h] = tv >= 0.f ? tv : NEG_SLOPE * tv;
                }
            }
#pragma unroll
            for (int h = 0; h < 4; ++h) m[h] = v[h];
#pragma unroll
            for (int mk = 1; mk <= 8; mk <<= 1)
#pragma unroll
                for (int h = 0; h < 4; ++h) m[h] = fmaxf(m[h], __shfl_xor(m[h], mk));
            float w[4];
#pragma unroll
            for (int h = 0; h < 4; ++h) w[h] = act ? __expf(v[h] - m[h]) : 0.f;
#pragma unroll
            for (int h = 0; h < 4; ++h) z[h] = w[h];
#pragma unroll
            for (int mk = 1; mk <= 8; mk <<= 1)
#pragma unroll
                for (int h = 0; h < 4; ++h) z[h] += __shfl_xor(z[h], mk);
#pragma unroll
            for (int h = 0; h < 4; ++h) wn[h] = w[h] / (z[h] + 1e-16f);
        } else {
#pragma unroll
            for (int h = 0; h < 4; ++h) m[h] = -1e30f;
            for (int e = beg + l16; e < end; e += 16) {
                const int s = csrc[e];
                const float4 sp = *(const float4*)&ssrc[(size_t)s * 4];
                const float s4[4] = { sp.x, sp.y, sp.z, sp.w };
#pragma unroll
                for (int h = 0; h < 4; ++h) {
                    float tv = s4[h] + sd[h];
                    tv = tv >= 0.f ? tv : NEG_SLOPE * tv;
                    m[h] = fmaxf(m[h], tv);
                }
            }
#pragma unroll
            for (int mk = 1; mk <= 8; mk <<= 1)
#pragma unroll
                for (int h = 0; h < 4; ++h) m[h] = fmaxf(m[h], __shfl_xor(m[h], mk));
#pragma unroll
            for (int h = 0; h < 4; ++h) z[h] = 0.f;
            for (int e = beg + l16; e < end; e += 16) {
                const int s = csrc[e];
                const float4 sp = *(const float4*)&ssrc[(size_t)s * 4];
                const float s4[4] = { sp.x, sp.y, sp.z, sp.w };
#pragma unroll
                for (int h = 0; h < 4; ++h) {
                    float tv = s4[h] + sd[h];
                    tv = tv >= 0.f ? tv : NEG_SLOPE * tv;
                    z[h] += __expf(tv - m[h]);
                }
            }
#pragma unroll
            for (int mk = 1; mk <= 8; mk <<= 1)
#pragma unroll
                for (int h = 0; h < 4; ++h) z[h] += __shfl_xor(z[h], mk);
        }

        const int c8 = l16 * 8;
        float ac[4][8];
#pragma unroll
        for (int h = 0; h < 4; ++h)
#pragma unroll
            for (int j = 0; j < 8; ++j) ac[h][j] = 0.f;

        if (fast) {
            int e = 0;
            for (; e + 2 <= deg; e += 2) {
                const int s0 = __shfl(myS, e + 0, 16);
                const int s1 = __shfl(myS, e + 1, 16);
                const uint4 u0 = *(const uint4*)&X16[(size_t)s0 * 128 + c8];
                const uint4 u1 = *(const uint4*)&X16[(size_t)s1 * 128 + c8];
                float w0[4], w1[4];
#pragma unroll
                for (int h = 0; h < 4; ++h) {
                    w0[h] = __shfl(wn[h], e + 0, 16);
                    w1[h] = __shfl(wn[h], e + 1, 16);
                }
                float f[8];
                unp8(u0, f);
#pragma unroll
                for (int h = 0; h < 4; ++h)
#pragma unroll
                    for (int j = 0; j < 8; ++j) ac[h][j] = fmaf(w0[h], f[j], ac[h][j]);
                unp8(u1, f);
#pragma unroll
                for (int h = 0; h < 4; ++h)
#pragma unroll
                    for (int j = 0; j < 8; ++j) ac[h][j] = fmaf(w1[h], f[j], ac[h][j]);
            }
            for (; e < deg; ++e) {
                const int s = __shfl(myS, e, 16);
                float wr[4];
                wr[0] = __shfl(wn[0], e, 16);
                wr[1] = __shfl(wn[1], e, 16);
                wr[2] = __shfl(wn[2], e, 16);
                wr[3] = __shfl(wn[3], e, 16);
                const uint4 u = *(const uint4*)&X16[(size_t)s * 128 + c8];
                float f[8]; unp8(u, f);
#pragma unroll
                for (int h = 0; h < 4; ++h)
#pragma unroll
                    for (int j = 0; j < 8; ++j) ac[h][j] = fmaf(wr[h], f[j], ac[h][j]);
            }
        } else {
            float ivh[4];
#pragma unroll
            for (int h = 0; h < 4; ++h) ivh[h] = 1.f / (z[h] + 1e-16f);
            for (int e = beg; e < end; ++e) {
                const int s = csrc[e];
                const float4 sp = *(const float4*)&ssrc[(size_t)s * 4];
                const float s4[4] = { sp.x, sp.y, sp.z, sp.w };
                float wr[4];
#pragma unroll
                for (int h = 0; h < 4; ++h) {
                    float tv = s4[h] + sd[h];
                    tv = tv >= 0.f ? tv : NEG_SLOPE * tv;
                    wr[h] = __expf(tv - m[h]) * ivh[h];
                }
                const uint4 u = *(const uint4*)&X16[(size_t)s * 128 + c8];
                float f[8]; unp8(u, f);
#pragma unroll
                for (int h = 0; h < 4; ++h)
#pragma unroll
                    for (int j = 0; j < 8; ++j) ac[h][j] = fmaf(wr[h], f[j], ac[h][j]);
            }
        }

#pragma unroll
        for (int h = 0; h < 4; ++h) {
            uint4 u;
            u.x = (unsigned int)f2h(ac[h][0]) | ((unsigned int)f2h(ac[h][1]) << 16);
            u.y = (unsigned int)f2h(ac[h][2]) | ((unsigned int)f2h(ac[h][3]) << 16);
            u.z = (unsigned int)f2h(ac[h][4]) | ((unsigned int)f2h(ac[h][5]) << 16);
            u.w = (unsigned int)f2h(ac[h][6]) | ((unsigned int)f2h(ac[h][7]) << 16);
            *(uint4*)&aggS[h][r][c8] = u;
        }
    }
    __syncthreads();

    // ---- phase 2: 16x128 GEMM, K=512, A from LDS, hi-plane W only
    const int wv   = t >> 6;
    const int lane = t & 63;
    const int quad = lane >> 4;
    const int q16  = lane & 15;

    floatx4 acc[2];
#pragma unroll
    for (int nt = 0; nt < 2; ++nt) acc[nt] = (floatx4){0.f, 0.f, 0.f, 0.f};

#pragma unroll
    for (int kc = 0; kc < 4; ++kc) {
        const unsigned short* whc = whf + kc * 16384;
#pragma unroll
        for (int ks = 0; ks < 4; ++ks) {
            const int ko = ks * 32 + quad * 8;
            half8 ah, bh[2];
            ah = *(const half8*)&aggS[kc][q16][ko];
#pragma unroll
            for (int nt = 0; nt < 2; ++nt)
                bh[nt] = *(const half8*)&whc[(((wv * 2 + nt) * 4 + ks) * 64 + lane) * 8];
#pragma unroll
            for (int nt = 0; nt < 2; ++nt)
                acc[nt] = __builtin_amdgcn_mfma_f32_16x16x32_f16(ah, bh[nt], acc[nt], 0, 0, 0);
        }
    }

    const int rl = quad * 4;
#pragma unroll
    for (int r = 0; r < 4; ++r) {
        const int grow = row0 + rl + r;
        if (grow < N) {
#pragma unroll
            for (int nt = 0; nt < 2; ++nt) {
                const int col = wv * 32 + nt * 16 + q16;
                const size_t ix = (size_t)grow * 128 + col;
                const float resid = us2f(X16[ix]) + us2f(Xl16[ix]);
                const float v = acc[nt][r] * 0.25f + ldx(bias, col, bf) + resid;
                if (bf) ((unsigned short*)out)[ix] = f2us(v);
                else    ((float*)out)[ix] = v;
            }
        }
    }
}

extern "C" void kernel_launch(void* const* d_in, const int* in_sizes, int n_in,
                              void* d_out, int out_size, void* d_ws, size_t ws_size,
                              hipStream_t stream) {
    const int N  = in_sizes[0] / 128;
    const int E  = in_sizes[1] / 2;
    const int EP = E + N;

    const void* x   = d_in[0];
    const void* ei  = d_in[1];
    const void* W1  = d_in[2];
    const void* as1 = d_in[3];
    const void* ad1 = d_in[4];
    const void* b1  = d_in[5];
    const void* W2  = d_in[6];
    const void* as2 = d_in[7];
    const void* ad2 = d_in[8];
    const void* b2  = d_in[9];
    const void* W3  = d_in[10];
    const void* as3 = d_in[11];
    const void* ad3 = d_in[12];
    const void* b3  = d_in[13];

    char* p = (char*)d_ws;
    auto alloc = [&](size_t bytes) { char* r = p; p += (bytes + 255) & ~(size_t)255; return r; };
    int*   flags = (int*)alloc(8);
    int*   deg   = (int*)alloc((size_t)(N + 1) * 4);
    int*   coff  = (int*)alloc((size_t)(N + 1) * 4);
    int*   cpos  = (int*)alloc((size_t)N * 4);
    int*   part  = (int*)alloc(4096);
    int*   csrc  = (int*)alloc((size_t)EP * 4);
    unsigned short* x1h = (unsigned short*)alloc((size_t)N * 128 * 2);   // x1 hi plane
    unsigned short* x1l = (unsigned short*)alloc((size_t)N * 128 * 2);   // x1 lo plane
    unsigned short* h16_12 = (unsigned short*)alloc((size_t)N * 128 * 2);  // h tables L1/L2
    float* ssrc  = (float*)alloc((size_t)N * 4 * 4);
    float* sdst  = (float*)alloc((size_t)N * 4 * 4);
    unsigned short* whf1 = (unsigned short*)alloc(16384 * 2);
    unsigned short* wlf1 = (unsigned short*)alloc(16384 * 2);
    unsigned short* whf2 = (unsigned short*)alloc(16384 * 2);
    unsigned short* wlf2 = (unsigned short*)alloc(16384 * 2);
    unsigned short* whf3 = (unsigned short*)alloc(65536 * 2);
    unsigned short* wlf3 = (unsigned short*)alloc(65536 * 2);
    unsigned short* vaf1h = (unsigned short*)alloc(8192 * 2);
    unsigned short* vaf1l = (unsigned short*)alloc(8192 * 2);
    unsigned short* vaf2h = (unsigned short*)alloc(8192 * 2);
    unsigned short* vaf2l = (unsigned short*)alloc(8192 * 2);
    unsigned short* x2h  = (unsigned short*)alloc((size_t)N * 128 * 2);   // x2 hi plane
    unsigned short* x2l  = (unsigned short*)alloc((size_t)N * 128 * 2);   // x2 lo plane
    float* va    = (float*)alloc(128 * 8 * 4);
    float* ssrc3 = (float*)alloc((size_t)N * 4 * 4);
    float* sdst3 = (float*)alloc((size_t)N * 4 * 4);

    hipMemsetAsync(deg,  0, (size_t)(N + 1) * 4, stream);
    hipMemsetAsync(cpos, 0, (size_t)N * 4, stream);

    k_detect<<<1, 64, 0, stream>>>((const unsigned short*)x, (const unsigned int*)ei, flags);

    k_wfrag<0><<<64, 256, 0, stream>>>(W1, flags, 128, 16384, whf1, wlf1);
    k_wfrag<0><<<64, 256, 0, stream>>>(W2, flags, 128, 16384, whf2, wlf2);
    k_wfrag<1><<<256, 256, 0, stream>>>(W3, flags, 512, 65536, whf3, wlf3);
    k_vaf<<<32, 256, 0, stream>>>(W1, as1, ad1, flags, vaf1h, vaf1l);
    k_vaf<<<32, 256, 0, stream>>>(W2, as2, ad2, flags, vaf2h, vaf2l);
    k_wa<<<2, 256, 0, stream>>>(W3, as3, ad3, flags, va);

    const int egrid = (EP + 255) / 256;
    const int nblk  = (N + 1023) / 1024;
    k_hist<<<egrid, 256, 0, stream>>>(ei, flags, deg, E, N);
    k_scan_a<<<nblk, 1024, 0, stream>>>(deg, coff, part, N);
    k_scan_b<<<1, 1024, 0, stream>>>(part, coff, nblk, N);
    k_scan_c<<<nblk, 1024, 0, stream>>>(coff, part, N);
    k_scatter<<<egrid, 256, 0, stream>>>(ei, flags, coff, cpos, csrc, E, N);

    const int ggrid = (N + 63) / 64;
    const int ngrid = (N + 15) / 16;

    // ---- layer 1 (scores via in-GEMM MFMA columns)
    k_gemm<0><<<ggrid, 256, 0, stream>>>(x, nullptr, whf1, wlf1, vaf1h, vaf1l,
                                         h16_12, ssrc, sdst, flags, N);
    k_agg<0><<<ngrid, 256, 0, stream>>>(coff, csrc, ssrc, sdst, h16_12, b1, x, nullptr,
                                        flags, N, nullptr, nullptr, nullptr, x1h, x1l);

    // ---- layer 2 (A from x1 hi/lo planes; epilogue emits x2 planes + layer-3 scores)
    k_gemm<1><<<ggrid, 256, 0, stream>>>(x1h, x1l, whf2, wlf2, vaf2h, vaf2l,
                                         h16_12, ssrc, sdst, flags, N);
    k_agg<1><<<ngrid, 256, 0, stream>>>(coff, csrc, ssrc, sdst, h16_12, b2, x1h, x1l,
                                        flags, N, va, ssrc3, sdst3, x2h, x2l);

    // ---- layer 3: fused aggregate-first gather -> LDS -> K=512 GEMM -> d_out
    k_aggx3<<<ngrid, 256, 0, stream>>>(coff, csrc, ssrc3, sdst3, x2h, x2l,
                                       whf3, b3, flags, d_out, N);
}

// Round 10
// 608.062 us; speedup vs baseline: 1.0413x; 1.0413x over previous
//
#include <hip/hip_runtime.h>
#include <hip/hip_bf16.h>
#include <cstdint>

#define NEG_SLOPE 0.2f

typedef __bf16 bf16x8 __attribute__((ext_vector_type(8)));
typedef _Float16 half8 __attribute__((ext_vector_type(8)));
typedef float  floatx4 __attribute__((ext_vector_type(4)));

// ---------- bf16 helpers ----------
__device__ __forceinline__ float us2f(unsigned short u) {
    union { unsigned int i; float f; } c; c.i = ((unsigned int)u) << 16; return c.f;
}
__device__ __forceinline__ unsigned short f2us(float f) {
    union { float f; unsigned int i; } c; c.f = f;
    unsigned int x = c.i;
    unsigned int r = (x + 0x7fffu + ((x >> 16) & 1u)) >> 16;   // RNE
    return (unsigned short)r;
}
__device__ __forceinline__ unsigned short f2h(float f) {
    union { _Float16 h; unsigned short u; } c; c.h = (_Float16)f; return c.u;
}
__device__ __forceinline__ float h2f(unsigned short u) {
    union { _Float16 h; unsigned short u; } c; c.u = u; return (float)c.h;
}
__device__ __forceinline__ float ldx(const void* p, int i, int bf) {
    return bf ? us2f(((const unsigned short*)p)[i]) : ((const float*)p)[i];
}
__device__ __forceinline__ void split2(float f, unsigned short& h, unsigned short& l) {
    h = f2us(f);
    l = f2us(f - us2f(h));
}
__device__ __forceinline__ float sel4(const float* a, int i) {
    float lo = (i & 1) ? a[1] : a[0];
    float hi = (i & 1) ? a[3] : a[2];
    return (i & 2) ? hi : lo;
}
__device__ __forceinline__ void unp8(uint4 u, float* f) {
    union { unsigned int i; float ff; } a;
    a.i = u.x << 16;          f[0] = a.ff;
    a.i = u.x & 0xffff0000u;  f[1] = a.ff;
    a.i = u.y << 16;          f[2] = a.ff;
    a.i = u.y & 0xffff0000u;  f[3] = a.ff;
    a.i = u.z << 16;          f[4] = a.ff;
    a.i = u.z & 0xffff0000u;  f[5] = a.ff;
    a.i = u.w << 16;          f[6] = a.ff;
    a.i = u.w & 0xffff0000u;  f[7] = a.ff;
}

// ---------- runtime dtype probes ----------
__global__ void k_detect(const unsigned short* __restrict__ x16,
                         const unsigned int* __restrict__ ei,
                         int* __restrict__ flags) {
    if (threadIdx.x == 0 && blockIdx.x == 0) {
        int cnt = 0;
        for (int i = 0; i < 1024; ++i) {
            const unsigned short u = x16[2 * i];
            const int e = (u >> 7) & 0xFF;
            if (e < 100 || e > 160) ++cnt;
        }
        flags[0] = (cnt < 256) ? 1 : 0;      // bf16?
        int is64 = 1;
        for (int i = 0; i < 64; ++i)
            if (ei[2 * i + 1] != 0u) { is64 = 0; break; }
        flags[1] = is64;                      // int64?
    }
}

__device__ __forceinline__ int edge_at(const void* ei, int f64, long long idx) {
    if (f64) return (int)((const long long*)ei)[idx];
    return ((const int*)ei)[idx];
}

// ---------- CSR build ----------
__global__ void k_hist(const void* __restrict__ ei, const int* __restrict__ flags,
                       int* __restrict__ deg, int E, int N) {
    const int f64 = flags[1];
    const int EP = E + N;
    for (int e = blockIdx.x * blockDim.x + threadIdx.x; e < EP; e += gridDim.x * blockDim.x) {
        int dst = (e < E) ? edge_at(ei, f64, (long long)E + e) : (e - E);
        atomicAdd(&deg[dst], 1);
    }
}

__global__ __launch_bounds__(1024) void k_scan_a(const int* __restrict__ deg,
                                                 int* __restrict__ coff,
                                                 int* __restrict__ part, int N) {
    __shared__ int tmp[1024];
    const int t = threadIdx.x, idx = blockIdx.x * 1024 + t;
    const int v = (idx < N) ? deg[idx] : 0;
    tmp[t] = v; __syncthreads();
    for (int s = 1; s < 1024; s <<= 1) {
        int a = (t >= s) ? tmp[t - s] : 0;
        __syncthreads(); tmp[t] += a; __syncthreads();
    }
    if (idx < N) coff[idx] = tmp[t] - v;
    if (t == 1023) part[blockIdx.x] = tmp[1023];
}

__global__ __launch_bounds__(1024) void k_scan_b(int* __restrict__ part,
                                                 int* __restrict__ coff, int nblk, int N) {
    __shared__ int tmp[1024];
    const int t = threadIdx.x;
    const int v = (t < nblk) ? part[t] : 0;
    tmp[t] = v; __syncthreads();
    for (int s = 1; s < 1024; s <<= 1) {
        int a = (t >= s) ? tmp[t - s] : 0;
        __syncthreads(); tmp[t] += a; __syncthreads();
    }
    if (t < nblk) part[t] = tmp[t] - v;
    if (t == 1023) coff[N] = tmp[1023];
}

__global__ __launch_bounds__(1024) void k_scan_c(int* __restrict__ coff,
                                                 const int* __restrict__ part, int N) {
    const int idx = blockIdx.x * 1024 + threadIdx.x;
    if (idx < N) coff[idx] += part[blockIdx.x];
}

__global__ void k_scatter(const void* __restrict__ ei, const int* __restrict__ flags,
                          const int* __restrict__ coff, int* __restrict__ cpos,
                          int* __restrict__ csrc, int E, int N) {
    const int f64 = flags[1];
    const int EP = E + N;
    for (int e = blockIdx.x * blockDim.x + threadIdx.x; e < EP; e += gridDim.x * blockDim.x) {
        int src, dst;
        if (e < E) { src = edge_at(ei, f64, e); dst = edge_at(ei, f64, (long long)E + e); }
        else       { src = dst = e - E; }
        const int p = atomicAdd(&cpos[dst], 1);
        csrc[coff[dst] + p] = src;
    }
}

// ---------- W -> MFMA B-fragment pre-shuffle (hi/lo planes) ----------
// F16=0: bf16 hi/lo planes (layers 1-2). F16=1: f16 hi/lo planes (layer 3).
template <int F16>
__global__ void k_wfrag(const void* __restrict__ Wv, const int* __restrict__ flags,
                        int wstride, int total,
                        unsigned short* __restrict__ outH, unsigned short* __restrict__ outL) {
    const int bf = flags[0];
    for (int tid = blockIdx.x * blockDim.x + threadIdx.x; tid < total;
         tid += gridDim.x * blockDim.x) {
        const int j    = tid & 7;
        const int lane = (tid >> 3) & 63;
        const int ks   = (tid >> 9) & 3;
        const int ntg  = (tid >> 11) & 7;
        const int blk  = tid >> 14;
        const int k = ks * 32 + (lane >> 4) * 8 + j;
        const int c = blk * 128 + ntg * 16 + (lane & 15);
        const float v = ldx(Wv, k * wstride + c, bf);
        unsigned short h, l;
        if (F16) {
            h = f2h(v);
            l = f2h(v - h2f(h));
        } else {
            split2(v, h, l);
        }
        outH[tid] = h; outL[tid] = l;
    }
}

// ---------- va[k,h] = sum_c W3[k, h*128+c] * a[h,c]  (layer-3 score folding) ----------
__global__ void k_wa(const void* __restrict__ W, const void* __restrict__ as,
                     const void* __restrict__ ad, const int* __restrict__ flags,
                     float* __restrict__ va) {
    const int bf = flags[0];
    const int t = blockIdx.x * blockDim.x + threadIdx.x;
    if (t >= 512) return;
    const int k = t >> 2, h = t & 3;
    float ss = 0.f, dd = 0.f;
    for (int c = 0; c < 128; ++c) {
        const float w = ldx(W, k * 512 + h * 128 + c, bf);
        ss = fmaf(w, ldx(as, h * 128 + c, bf), ss);
        dd = fmaf(w, ldx(ad, h * 128 + c, bf), dd);
    }
    va[k * 8 + h] = ss;
    va[k * 8 + 4 + h] = dd;
}

// ---------- MFMA GEMM with fused scores epilogue (layers 1-2) ----------
template <bool XRAW, int SC>
__global__ __launch_bounds__(256) void k_gemm(const void* __restrict__ Xv,
                                              const unsigned short* __restrict__ whfB,
                                              const unsigned short* __restrict__ wlfB,
                                              unsigned short* __restrict__ Y16, int ystride,
                                              float* __restrict__ ssrc,
                                              float* __restrict__ sdst,
                                              const void* __restrict__ a_src,
                                              const void* __restrict__ a_dst,
                                              const int* __restrict__ flags,
                                              int N) {
    __shared__ __align__(16) unsigned short Ah[64][136], Al[64][136];
    __shared__ float sred[2][4][SC ? 64 : 1];
    const int bf   = flags[0];
    const int t    = threadIdx.x;
    const int row0 = blockIdx.x * 64;
    const int hy   = blockIdx.y;
    const unsigned short* whf = whfB + hy * 16384;
    const unsigned short* wlf = wlfB + hy * 16384;
    const int ycol0 = hy * 128;
    const int wv   = t >> 6;
    const int lane = t & 63;
    const int quad = lane >> 4;
    const int l16  = lane & 15;

#pragma unroll
    for (int it = 0; it < 8; ++it) {
        const int id = it * 256 + t;
        const int r  = id >> 5;
        const int c  = (id & 31) * 4;
        const int gr = row0 + r;
        ushort4 h4 = make_ushort4(0, 0, 0, 0), l4 = make_ushort4(0, 0, 0, 0);
        if (gr < N) {
            if (XRAW && bf) {
                h4 = *(const ushort4*)&((const unsigned short*)Xv)[(size_t)gr * 128 + c];
            } else {
                const float4 f = *(const float4*)&((const float*)Xv)[(size_t)gr * 128 + c];
                split2(f.x, h4.x, l4.x); split2(f.y, h4.y, l4.y);
                split2(f.z, h4.z, l4.z); split2(f.w, h4.w, l4.w);
            }
        }
        *(ushort4*)&Ah[r][c] = h4;
        *(ushort4*)&Al[r][c] = l4;
    }
    __syncthreads();

    floatx4 acc[4][2];
#pragma unroll
    for (int mt = 0; mt < 4; ++mt)
#pragma unroll
        for (int nt = 0; nt < 2; ++nt) acc[mt][nt] = (floatx4){0.f, 0.f, 0.f, 0.f};

#pragma unroll
    for (int ks = 0; ks < 4; ++ks) {
        const int ko = ks * 32 + quad * 8;
        bf16x8 ah[4], al[4], bh[2], bl[2];
#pragma unroll
        for (int mt = 0; mt < 4; ++mt) ah[mt] = *(const bf16x8*)&Ah[mt * 16 + l16][ko];
        if (!(XRAW && bf)) {
#pragma unroll
            for (int mt = 0; mt < 4; ++mt) al[mt] = *(const bf16x8*)&Al[mt * 16 + l16][ko];
        }
#pragma unroll
        for (int nt = 0; nt < 2; ++nt)
            bh[nt] = *(const bf16x8*)&whf[(((wv * 2 + nt) * 4 + ks) * 64 + lane) * 8];
        if (!bf) {
#pragma unroll
            for (int nt = 0; nt < 2; ++nt)
                bl[nt] = *(const bf16x8*)&wlf[(((wv * 2 + nt) * 4 + ks) * 64 + lane) * 8];
        }
#pragma unroll
        for (int mt = 0; mt < 4; ++mt)
#pragma unroll
            for (int nt = 0; nt < 2; ++nt) {
                acc[mt][nt] = __builtin_amdgcn_mfma_f32_16x16x32_bf16(ah[mt], bh[nt], acc[mt][nt], 0, 0, 0);
                if (!bf)
                    acc[mt][nt] = __builtin_amdgcn_mfma_f32_16x16x32_bf16(ah[mt], bl[nt], acc[mt][nt], 0, 0, 0);
                if (!(XRAW && bf))
                    acc[mt][nt] = __builtin_amdgcn_mfma_f32_16x16x32_bf16(al[mt], bh[nt], acc[mt][nt], 0, 0, 0);
            }
    }

    const int aBase = hy * 128 + wv * 32;
    float as_[2], ad_[2];
#pragma unroll
    for (int nt = 0; nt < 2; ++nt) {
        as_[nt] = ldx(a_src, aBase + nt * 16 + l16, bf);
        ad_[nt] = ldx(a_dst, aBase + nt * 16 + l16, bf);
    }

#pragma unroll
    for (int mt = 0; mt < 4; ++mt) {
        const int rl = mt * 16 + quad * 4;
#pragma unroll
        for (int r = 0; r < 4; ++r) {
            const int grow = row0 + rl + r;
            if (grow < N) {
#pragma unroll
                for (int nt = 0; nt < 2; ++nt)
                    Y16[(size_t)grow * ystride + ycol0 + wv * 32 + nt * 16 + l16] =
                        f2us(acc[mt][nt][r]);
            }
            float ps = acc[mt][0][r] * as_[0] + acc[mt][1][r] * as_[1];
            float pd = acc[mt][0][r] * ad_[0] + acc[mt][1][r] * ad_[1];
#pragma unroll
            for (int mk = 1; mk <= 8; mk <<= 1) {
                ps += __shfl_xor(ps, mk);
                pd += __shfl_xor(pd, mk);
            }
            if (SC == 0) {
                if (l16 == 0 && grow < N) {
                    ssrc[(size_t)grow * 4 + wv] = ps;
                    sdst[(size_t)grow * 4 + wv] = pd;
                }
            } else {
                if (l16 == 0) { sred[0][wv][rl + r] = ps; sred[1][wv][rl + r] = pd; }
            }
        }
    }
    if (SC == 1) {
        __syncthreads();
        if (t < 64 && row0 + t < N) {
            ssrc[(size_t)(row0 + t) * 4 + hy] = sred[0][0][t] + sred[0][1][t] + sred[0][2][t] + sred[0][3][t];
            sdst[(size_t)(row0 + t) * 4 + hy] = sred[1][0][t] + sred[1][1][t] + sred[1][2][t] + sred[1][3][t];
        }
    }
}

// ---------- softmax + aggregation; 16 lanes/node; shfl-broadcast fast path ----------
// NO-MAX softmax (layers 1-2 scores ~N(0,11), max << 88 overflow; guarded fmin 80).
// MODE 0: out = elu(acc + bias + raw resid) -> f32   (layer 1)
// MODE 1: x2 = elu(acc + bias + f32 resid) -> bf16 hi (x2h) + lo (x2l) planes only
//         (no f32 copy); also layer-3 scores ss2/sd2 via folded va
template <int MODE>
__global__ __launch_bounds__(256) void k_agg(const int* __restrict__ coff,
                                             const int* __restrict__ csrc,
                                             const float* __restrict__ ssrc,
                                             const float* __restrict__ sdst,
                                             const unsigned short* __restrict__ H16,
                                             const void* __restrict__ bias,
                                             const void* __restrict__ resid,
                                             const int* __restrict__ flags,
                                             void* __restrict__ out, int N,
                                             const float* __restrict__ va,
                                             float* __restrict__ ss2,
                                             float* __restrict__ sd2,
                                             unsigned short* __restrict__ x2h,
                                             unsigned short* __restrict__ x2l) {
    __shared__ float vaS[(MODE == 1) ? 128 : 1][10];   // pad 9->10: 4-way -> 2-way banks
    const int bf   = flags[0];
    const int t    = threadIdx.x;
    const int l16  = t & 15;
    const int n0   = blockIdx.x * 16 + (t >> 4);
    const bool nact = n0 < N;
    const int n    = nact ? n0 : (N - 1);
    const int beg = coff[n], end = coff[n + 1];
    const int deg = end - beg;

    if (MODE == 1) {
        for (int i = t; i < 1024; i += 256) vaS[i >> 3][i & 7] = va[i];
        __syncthreads();
    }

    const float4 sdv = *(const float4*)&sdst[(size_t)n * 4];
    const float sd[4] = { sdv.x, sdv.y, sdv.z, sdv.w };
    const bool fast = (deg <= 16);
    float z[4];
    int   myS = 0;
    float wn[4] = { 0.f, 0.f, 0.f, 0.f };     // raw exp weights (unnormalized)

    if (fast) {
        const bool act = l16 < deg;
        if (act) {
            myS = csrc[beg + l16];
            const float4 sp = *(const float4*)&ssrc[(size_t)myS * 4];
            const float s4[4] = { sp.x, sp.y, sp.z, sp.w };
#pragma unroll
            for (int h = 0; h < 4; ++h) {
                float tv = s4[h] + sd[h];
                tv = tv >= 0.f ? tv : NEG_SLOPE * tv;
                wn[h] = __expf(fminf(tv, 80.f));
            }
        }
#pragma unroll
        for (int h = 0; h < 4; ++h) z[h] = wn[h];
#pragma unroll
        for (int mk = 1; mk <= 8; mk <<= 1)
#pragma unroll
            for (int h = 0; h < 4; ++h) z[h] += __shfl_xor(z[h], mk);
    } else {
#pragma unroll
        for (int h = 0; h < 4; ++h) z[h] = 0.f;
        for (int e = beg + l16; e < end; e += 16) {
            const int s = csrc[e];
            const float4 sp = *(const float4*)&ssrc[(size_t)s * 4];
            const float s4[4] = { sp.x, sp.y, sp.z, sp.w };
#pragma unroll
            for (int h = 0; h < 4; ++h) {
                float tv = s4[h] + sd[h];
                tv = tv >= 0.f ? tv : NEG_SLOPE * tv;
                z[h] += __expf(fminf(tv, 80.f));
            }
        }
#pragma unroll
        for (int mk = 1; mk <= 8; mk <<= 1)
#pragma unroll
            for (int h = 0; h < 4; ++h) z[h] += __shfl_xor(z[h], mk);
    }

    float ivz[4];
#pragma unroll
    for (int h = 0; h < 4; ++h) ivz[h] = 1.f / (z[h] + 1e-16f);

    // gather: each lane owns 8 channels of its node (uint4 = 16 B per lane per edge)
    const int c8 = l16 * 8;
    const int hd = l16 >> 2;             // head owning channels c8..c8+7
    const float ih = sel4(ivz, hd);      // end-scale (1/z for this lane's head)
    float ac[8];
#pragma unroll
    for (int j = 0; j < 8; ++j) ac[j] = 0.f;

    if (fast) {
        for (int e = 0; e < deg; ++e) {
            const int s = __shfl(myS, e, 16);
            float wa4[4];
            wa4[0] = __shfl(wn[0], e, 16);
            wa4[1] = __shfl(wn[1], e, 16);
            wa4[2] = __shfl(wn[2], e, 16);
            wa4[3] = __shfl(wn[3], e, 16);
            const float w = sel4(wa4, hd);
            const uint4 u = *(const uint4*)&H16[(size_t)s * 128 + c8];
            float f[8]; unp8(u, f);
#pragma unroll
            for (int j = 0; j < 8; ++j) ac[j] = fmaf(w, f[j], ac[j]);
        }
    } else {
        const float sdh = sel4(sd, hd);
        for (int e = beg; e < end; ++e) {
            const int s = csrc[e];
            float tv = ssrc[(size_t)s * 4 + hd] + sdh;
            tv = tv >= 0.f ? tv : NEG_SLOPE * tv;
            const float w = __expf(fminf(tv, 80.f));
            const uint4 u = *(const uint4*)&H16[(size_t)s * 128 + c8];
            float f[8]; unp8(u, f);
#pragma unroll
            for (int j = 0; j < 8; ++j) ac[j] = fmaf(w, f[j], ac[j]);
        }
    }

    // normalize once (softmax 1/z)
#pragma unroll
    for (int j = 0; j < 8; ++j) ac[j] *= ih;

    if (!nact) return;
    const int ob = n * 128 + c8;
    float rr[8];
    if (MODE == 0) {
        if (bf) {
            const uint4 u = *(const uint4*)&((const unsigned short*)resid)[ob];
            unp8(u, rr);
        } else {
            const float4 r0 = *(const float4*)&((const float*)resid)[ob];
            const float4 r1 = *(const float4*)&((const float*)resid)[ob + 4];
            rr[0] = r0.x; rr[1] = r0.y; rr[2] = r0.z; rr[3] = r0.w;
            rr[4] = r1.x; rr[5] = r1.y; rr[6] = r1.z; rr[7] = r1.w;
        }
    } else {
        const float4 r0 = *(const float4*)&((const float*)resid)[ob];
        const float4 r1 = *(const float4*)&((const float*)resid)[ob + 4];
        rr[0] = r0.x; rr[1] = r0.y; rr[2] = r0.z; rr[3] = r0.w;
        rr[4] = r1.x; rr[5] = r1.y; rr[6] = r1.z; rr[7] = r1.w;
    }
    float o[8];
#pragma unroll
    for (int j = 0; j < 8; ++j) {
        const float v = ac[j] + ldx(bias, c8 + j, bf) + rr[j];
        o[j] = v > 0.f ? v : expm1f(v);
    }
    if (MODE == 0) {
        *(float4*)&((float*)out)[ob]     = make_float4(o[0], o[1], o[2], o[3]);
        *(float4*)&((float*)out)[ob + 4] = make_float4(o[4], o[5], o[6], o[7]);
    }

    if (MODE == 1) {
        // bf16 hi/lo planes: hi feeds the layer-3 gather; hi+lo reconstruct the
        // residual at ~f32 accuracy in the fused layer-3 epilogue.
        unsigned short hi[8], lo[8];
#pragma unroll
        for (int j = 0; j < 8; ++j) {
            hi[j] = f2us(o[j]);
            lo[j] = f2us(o[j] - us2f(hi[j]));
        }
        uint4 uh, ul;
        uh.x = (unsigned int)hi[0] | ((unsigned int)hi[1] << 16);
        uh.y = (unsigned int)hi[2] | ((unsigned int)hi[3] << 16);
        uh.z = (unsigned int)hi[4] | ((unsigned int)hi[5] << 16);
        uh.w = (unsigned int)hi[6] | ((unsigned int)hi[7] << 16);
        ul.x = (unsigned int)lo[0] | ((unsigned int)lo[1] << 16);
        ul.y = (unsigned int)lo[2] | ((unsigned int)lo[3] << 16);
        ul.z = (unsigned int)lo[4] | ((unsigned int)lo[5] << 16);
        ul.w = (unsigned int)lo[6] | ((unsigned int)lo[7] << 16);
        *(uint4*)&x2h[ob] = uh;
        *(uint4*)&x2l[ob] = ul;
        // layer-3 scores: s[n,h] = sum_k x2[n,k] * va[k,h] (f32-exact)
        float p[8];
#pragma unroll
        for (int o8 = 0; o8 < 8; ++o8) {
            float acc = 0.f;
#pragma unroll
            for (int j = 0; j < 8; ++j) acc = fmaf(o[j], vaS[c8 + j][o8], acc);
            p[o8] = acc;
        }
#pragma unroll
        for (int mk = 1; mk <= 8; mk <<= 1)
#pragma unroll
            for (int o8 = 0; o8 < 8; ++o8) p[o8] += __shfl_xor(p[o8], mk);
        if (l16 == 0) {
#pragma unroll
            for (int h = 0; h < 4; ++h) {
                ss2[(size_t)n * 4 + h] = p[h];
                sd2[(size_t)n * 4 + h] = p[4 + h];
            }
        }
    }
}

// ---------- FUSED layer 3: aggregate-first gather -> LDS -> K=512 MFMA GEMM ----------
// 16 nodes/block (LDS 17.4KB -> 8 blocks/CU). Phase 1: 16 lanes/node gather x2h
// (bf16, 25.6MB table) with max-subtracted softmax, aggregate per head into
// f16 LDS tile aggS[4 kc][16 rows][136]. Phase 2: GEMM vs whf3 hi-plane only
// (f16 A already limits precision; bf16-gather error dominates absmax),
// epilogue adds bias + hi/lo-bf16 residual, writes d_out.
__global__ __launch_bounds__(256) void k_aggx3(const int* __restrict__ coff,
                                               const int* __restrict__ csrc,
                                               const float* __restrict__ ssrc,
                                               const float* __restrict__ sdst,
                                               const unsigned short* __restrict__ X16,
                                               const unsigned short* __restrict__ Xl16,
                                               const unsigned short* __restrict__ whf,
                                               const void* __restrict__ bias,
                                               const int* __restrict__ flags,
                                               void* __restrict__ out, int N) {
    __shared__ __align__(16) unsigned short aggS[4][16][136];
    const int bf   = flags[0];
    const int t    = threadIdx.x;
    const int row0 = blockIdx.x * 16;
    const int l16  = t & 15;

    // ---- phase 1: aggregate 16 nodes into LDS (16 lanes per node)
    {
        const int r  = t >> 4;
        const int n0 = row0 + r;
        const int n  = (n0 < N) ? n0 : (N - 1);
        const int beg = coff[n], end = coff[n + 1];
        const int deg = end - beg;

        const float4 sdv = *(const float4*)&sdst[(size_t)n * 4];
        const float sd[4] = { sdv.x, sdv.y, sdv.z, sdv.w };
        const bool fast = (deg <= 16);
        float m[4], z[4];
        int   myS = 0;
        float wn[4] = { 0.f, 0.f, 0.f, 0.f };

        if (fast) {
            const bool act = l16 < deg;
            float v[4];
#pragma unroll
            for (int h = 0; h < 4; ++h) v[h] = -1e30f;
            if (act) {
                myS = csrc[beg + l16];
                const float4 sp = *(const float4*)&ssrc[(size_t)myS * 4];
                const float s4[4] = { sp.x, sp.y, sp.z, sp.w };
#pragma unroll
                for (int h = 0; h < 4; ++h) {
                    float tv = s4[h] + sd[h];
                    v[h] = tv >= 0.f ? tv : NEG_SLOPE * tv;
                }
            }
#pragma unroll
            for (int h = 0; h < 4; ++h) m[h] = v[h];
#pragma unroll
            for (int mk = 1; mk <= 8; mk <<= 1)
#pragma unroll
                for (int h = 0; h < 4; ++h) m[h] = fmaxf(m[h], __shfl_xor(m[h], mk));
            float w[4];
#pragma unroll
            for (int h = 0; h < 4; ++h) w[h] = act ? __expf(v[h] - m[h]) : 0.f;
#pragma unroll
            for (int h = 0; h < 4; ++h) z[h] = w[h];
#pragma unroll
            for (int mk = 1; mk <= 8; mk <<= 1)
#pragma unroll
                for (int h = 0; h < 4; ++h) z[h] += __shfl_xor(z[h], mk);
#pragma unroll
            for (int h = 0; h < 4; ++h) wn[h] = w[h] / (z[h] + 1e-16f);
        } else {
#pragma unroll
            for (int h = 0; h < 4; ++h) m[h] = -1e30f;
            for (int e = beg + l16; e < end; e += 16) {
                const int s = csrc[e];
                const float4 sp = *(const float4*)&ssrc[(size_t)s * 4];
                const float s4[4] = { sp.x, sp.y, sp.z, sp.w };
#pragma unroll
                for (int h = 0; h < 4; ++h) {
                    float tv = s4[h] + sd[h];
                    tv = tv >= 0.f ? tv : NEG_SLOPE * tv;
                    m[h] = fmaxf(m[h], tv);
                }
            }
#pragma unroll
            for (int mk = 1; mk <= 8; mk <<= 1)
#pragma unroll
                for (int h = 0; h < 4; ++h) m[h] = fmaxf(m[h], __shfl_xor(m[h], mk));
#pragma unroll
            for (int h = 0; h < 4; ++h) z[h] = 0.f;
            for (int e = beg + l16; e < end; e += 16) {
                const int s = csrc[e];
                const float4 sp = *(const float4*)&ssrc[(size_t)s * 4];
                const float s4[4] = { sp.x, sp.y, sp.z, sp.w };
#pragma unroll
                for (int h = 0; h < 4; ++h) {
                    float tv = s4[h] + sd[h];
                    tv = tv >= 0.f ? tv : NEG_SLOPE * tv;
                    z[h] += __expf(tv - m[h]);
                }
            }
#pragma unroll
            for (int mk = 1; mk <= 8; mk <<= 1)
#pragma unroll
                for (int h = 0; h < 4; ++h) z[h] += __shfl_xor(z[h], mk);
        }

        const int c8 = l16 * 8;
        float ac[4][8];
#pragma unroll
        for (int h = 0; h < 4; ++h)
#pragma unroll
            for (int j = 0; j < 8; ++j) ac[h][j] = 0.f;

        if (fast) {
            int e = 0;
            for (; e + 2 <= deg; e += 2) {
                const int s0 = __shfl(myS, e + 0, 16);
                const int s1 = __shfl(myS, e + 1, 16);
                const uint4 u0 = *(const uint4*)&X16[(size_t)s0 * 128 + c8];
                const uint4 u1 = *(const uint4*)&X16[(size_t)s1 * 128 + c8];
                float w0[4], w1[4];
#pragma unroll
                for (int h = 0; h < 4; ++h) {
                    w0[h] = __shfl(wn[h], e + 0, 16);
                    w1[h] = __shfl(wn[h], e + 1, 16);
                }
                float f[8];
                unp8(u0, f);
#pragma unroll
                for (int h = 0; h < 4; ++h)
#pragma unroll
                    for (int j = 0; j < 8; ++j) ac[h][j] = fmaf(w0[h], f[j], ac[h][j]);
                unp8(u1, f);
#pragma unroll
                for (int h = 0; h < 4; ++h)
#pragma unroll
                    for (int j = 0; j < 8; ++j) ac[h][j] = fmaf(w1[h], f[j], ac[h][j]);
            }
            for (; e < deg; ++e) {
                const int s = __shfl(myS, e, 16);
                float wr[4];
                wr[0] = __shfl(wn[0], e, 16);
                wr[1] = __shfl(wn[1], e, 16);
                wr[2] = __shfl(wn[2], e, 16);
                wr[3] = __shfl(wn[3], e, 16);
                const uint4 u = *(const uint4*)&X16[(size_t)s * 128 + c8];
                float f[8]; unp8(u, f);
#pragma unroll
                for (int h = 0; h < 4; ++h)
#pragma unroll
                    for (int j = 0; j < 8; ++j) ac[h][j] = fmaf(wr[h], f[j], ac[h][j]);
            }
        } else {
            float ivh[4];
#pragma unroll
            for (int h = 0; h < 4; ++h) ivh[h] = 1.f / (z[h] + 1e-16f);
            for (int e = beg; e < end; ++e) {
                const int s = csrc[e];
                const float4 sp = *(const float4*)&ssrc[(size_t)s * 4];
                const float s4[4] = { sp.x, sp.y, sp.z, sp.w };
                float wr[4];
#pragma unroll
                for (int h = 0; h < 4; ++h) {
                    float tv = s4[h] + sd[h];
                    tv = tv >= 0.f ? tv : NEG_SLOPE * tv;
                    wr[h] = __expf(tv - m[h]) * ivh[h];
                }
                const uint4 u = *(const uint4*)&X16[(size_t)s * 128 + c8];
                float f[8]; unp8(u, f);
#pragma unroll
                for (int h = 0; h < 4; ++h)
#pragma unroll
                    for (int j = 0; j < 8; ++j) ac[h][j] = fmaf(wr[h], f[j], ac[h][j]);
            }
        }

#pragma unroll
        for (int h = 0; h < 4; ++h) {
            uint4 u;
            u.x = (unsigned int)f2h(ac[h][0]) | ((unsigned int)f2h(ac[h][1]) << 16);
            u.y = (unsigned int)f2h(ac[h][2]) | ((unsigned int)f2h(ac[h][3]) << 16);
            u.z = (unsigned int)f2h(ac[h][4]) | ((unsigned int)f2h(ac[h][5]) << 16);
            u.w = (unsigned int)f2h(ac[h][6]) | ((unsigned int)f2h(ac[h][7]) << 16);
            *(uint4*)&aggS[h][r][c8] = u;
        }
    }
    __syncthreads();

    // ---- phase 2: 16x128 GEMM, K=512, A from LDS, hi-plane W only
    const int wv   = t >> 6;
    const int lane = t & 63;
    const int quad = lane >> 4;
    const int q16  = lane & 15;

    floatx4 acc[2];
#pragma unroll
    for (int nt = 0; nt < 2; ++nt) acc[nt] = (floatx4){0.f, 0.f, 0.f, 0.f};

#pragma unroll
    for (int kc = 0; kc < 4; ++kc) {
        const unsigned short* whc = whf + kc * 16384;
#pragma unroll
        for (int ks = 0; ks < 4; ++ks) {
            const int ko = ks * 32 + quad * 8;
            half8 ah, bh[2];
            ah = *(const half8*)&aggS[kc][q16][ko];
#pragma unroll
            for (int nt = 0; nt < 2; ++nt)
                bh[nt] = *(const half8*)&whc[(((wv * 2 + nt) * 4 + ks) * 64 + lane) * 8];
#pragma unroll
            for (int nt = 0; nt < 2; ++nt)
                acc[nt] = __builtin_amdgcn_mfma_f32_16x16x32_f16(ah, bh[nt], acc[nt], 0, 0, 0);
        }
    }

    const int rl = quad * 4;
#pragma unroll
    for (int r = 0; r < 4; ++r) {
        const int grow = row0 + rl + r;
        if (grow < N) {
#pragma unroll
            for (int nt = 0; nt < 2; ++nt) {
                const int col = wv * 32 + nt * 16 + q16;
                const size_t ix = (size_t)grow * 128 + col;
                const float resid = us2f(X16[ix]) + us2f(Xl16[ix]);
                const float v = acc[nt][r] * 0.25f + ldx(bias, col, bf) + resid;
                if (bf) ((unsigned short*)out)[ix] = f2us(v);
                else    ((float*)out)[ix] = v;
            }
        }
    }
}

extern "C" void kernel_launch(void* const* d_in, const int* in_sizes, int n_in,
                              void* d_out, int out_size, void* d_ws, size_t ws_size,
                              hipStream_t stream) {
    const int N  = in_sizes[0] / 128;
    const int E  = in_sizes[1] / 2;
    const int EP = E + N;

    const void* x   = d_in[0];
    const void* ei  = d_in[1];
    const void* W1  = d_in[2];
    const void* as1 = d_in[3];
    const void* ad1 = d_in[4];
    const void* b1  = d_in[5];
    const void* W2  = d_in[6];
    const void* as2 = d_in[7];
    const void* ad2 = d_in[8];
    const void* b2  = d_in[9];
    const void* W3  = d_in[10];
    const void* as3 = d_in[11];
    const void* ad3 = d_in[12];
    const void* b3  = d_in[13];

    char* p = (char*)d_ws;
    auto alloc = [&](size_t bytes) { char* r = p; p += (bytes + 255) & ~(size_t)255; return r; };
    int*   flags = (int*)alloc(8);
    int*   deg   = (int*)alloc((size_t)(N + 1) * 4);
    int*   coff  = (int*)alloc((size_t)(N + 1) * 4);
    int*   cpos  = (int*)alloc((size_t)N * 4);
    int*   part  = (int*)alloc(4096);
    int*   csrc  = (int*)alloc((size_t)EP * 4);
    float* x1b   = (float*)alloc((size_t)N * 128 * 4);            // layer-1 out f32
    unsigned short* h16_12 = (unsigned short*)alloc((size_t)N * 128 * 2);  // h tables L1/L2
    float* ssrc  = (float*)alloc((size_t)N * 4 * 4);
    float* sdst  = (float*)alloc((size_t)N * 4 * 4);
    unsigned short* whf1 = (unsigned short*)alloc(16384 * 2);
    unsigned short* wlf1 = (unsigned short*)alloc(16384 * 2);
    unsigned short* whf2 = (unsigned short*)alloc(16384 * 2);
    unsigned short* wlf2 = (unsigned short*)alloc(16384 * 2);
    unsigned short* whf3 = (unsigned short*)alloc(65536 * 2);
    unsigned short* wlf3 = (unsigned short*)alloc(65536 * 2);
    unsigned short* x2h  = (unsigned short*)alloc((size_t)N * 128 * 2);   // x2 hi plane
    unsigned short* x2l  = (unsigned short*)alloc((size_t)N * 128 * 2);   // x2 lo plane
    float* va    = (float*)alloc(128 * 8 * 4);
    float* ssrc3 = (float*)alloc((size_t)N * 4 * 4);
    float* sdst3 = (float*)alloc((size_t)N * 4 * 4);

    hipMemsetAsync(deg,  0, (size_t)(N + 1) * 4, stream);
    hipMemsetAsync(cpos, 0, (size_t)N * 4, stream);

    k_detect<<<1, 64, 0, stream>>>((const unsigned short*)x, (const unsigned int*)ei, flags);

    k_wfrag<0><<<64, 256, 0, stream>>>(W1, flags, 128, 16384, whf1, wlf1);
    k_wfrag<0><<<64, 256, 0, stream>>>(W2, flags, 128, 16384, whf2, wlf2);
    k_wfrag<1><<<256, 256, 0, stream>>>(W3, flags, 512, 65536, whf3, wlf3);
    k_wa<<<2, 256, 0, stream>>>(W3, as3, ad3, flags, va);

    const int egrid = (EP + 255) / 256;
    const int nblk  = (N + 1023) / 1024;
    k_hist<<<egrid, 256, 0, stream>>>(ei, flags, deg, E, N);
    k_scan_a<<<nblk, 1024, 0, stream>>>(deg, coff, part, N);
    k_scan_b<<<1, 1024, 0, stream>>>(part, coff, nblk, N);
    k_scan_c<<<nblk, 1024, 0, stream>>>(coff, part, N);
    k_scatter<<<egrid, 256, 0, stream>>>(ei, flags, coff, cpos, csrc, E, N);

    const int ggrid = (N + 63) / 64;
    const int ngrid = (N + 15) / 16;

    // ---- layer 1
    k_gemm<true, 0><<<dim3(ggrid, 1), 256, 0, stream>>>(x, whf1, wlf1, h16_12, 128,
                                                        ssrc, sdst, as1, ad1, flags, N);
    k_agg<0><<<ngrid, 256, 0, stream>>>(coff, csrc, ssrc, sdst, h16_12, b1, x, flags, x1b, N,
                                        nullptr, nullptr, nullptr, nullptr, nullptr);

    // ---- layer 2 (epilogue emits x2 hi/lo bf16 planes + layer-3 scores via folded va)
    k_gemm<false, 0><<<dim3(ggrid, 1), 256, 0, stream>>>(x1b, whf2, wlf2, h16_12, 128,
                                                         ssrc, sdst, as2, ad2, flags, N);
    k_agg<1><<<ngrid, 256, 0, stream>>>(coff, csrc, ssrc, sdst, h16_12, b2, x1b, flags, nullptr, N,
                                        va, ssrc3, sdst3, x2h, x2l);

    // ---- layer 3: fused aggregate-first gather -> LDS -> K=512 GEMM -> d_out
    k_aggx3<<<ngrid, 256, 0, stream>>>(coff, csrc, ssrc3, sdst3, x2h, x2l,
                                       whf3, b3, flags, d_out, N);
}